// Round 1
// baseline (741.275 us; speedup 1.0000x reference)
//
#include <hip/hip_runtime.h>
#include <hip/hip_bf16.h>
#include <cstdint>
#include <cstddef>

#define NTOK 2048
#define HID  2048
#define NINT 5632
#define NEXP 8

typedef __attribute__((ext_vector_type(8))) short short8;
typedef __attribute__((ext_vector_type(4))) float f32x4;
typedef __attribute__((ext_vector_type(4))) int   int4v;
typedef __attribute__((ext_vector_type(4))) float fl4;

__device__ __forceinline__ unsigned short f2bf(float f) {
    union { float f; unsigned int u; } v; v.f = f;
    unsigned int r = (v.u + 0x7fffu + ((v.u >> 16) & 1u)) >> 16;
    return (unsigned short)r;
}

// meta layout (ints): [0..7]=cnt, [8..15]=cursor, [16..24]=offs
__global__ void zero_kernel(float* __restrict__ out, int* __restrict__ meta) {
    int idx = blockIdx.x * blockDim.x + threadIdx.x;   // 4096 x 256, 4 floats each = 4,194,304
    fl4 z = {0.f, 0.f, 0.f, 0.f};
    ((fl4*)out)[idx] = z;
    if (blockIdx.x == 0 && threadIdx.x < 16) meta[threadIdx.x] = 0;
}

__device__ __forceinline__ void top2_route(const float* __restrict__ lg, int t,
                                           int& e0, int& e1, float& w0, float& w1) {
    float l[NEXP];
#pragma unroll
    for (int e = 0; e < NEXP; ++e) l[e] = lg[t * NEXP + e];
    // argmax on raw logits (exact; exp is monotone)
    e0 = 0; float b0l = l[0];
#pragma unroll
    for (int e = 1; e < NEXP; ++e) if (l[e] > b0l) { b0l = l[e]; e0 = e; }
    e1 = (e0 == 0) ? 1 : 0; float b1l = l[e1];
#pragma unroll
    for (int e = 0; e < NEXP; ++e) {
        if (e == e0) continue;
        if (l[e] > b1l) { b1l = l[e]; e1 = e; }
    }
    // renormalized top-2 softmax weights: exp(l0-m)/(exp(l0-m)+exp(l1-m))
    float m = b0l;
    float p0 = __expf(b0l - m), p1 = __expf(b1l - m);
    float inv = 1.f / (p0 + p1);
    w0 = p0 * inv; w1 = p1 * inv;
}

__global__ void route_count(const float* __restrict__ logits, int* __restrict__ meta) {
    int t = blockIdx.x * blockDim.x + threadIdx.x;   // 8 x 256 = 2048
    int e0, e1; float w0, w1;
    top2_route(logits, t, e0, e1, w0, w1);
    atomicAdd(&meta[e0], 1);
    atomicAdd(&meta[e1], 1);
}

__global__ void scan_kernel(int* __restrict__ meta) {
    if (threadIdx.x == 0 && blockIdx.x == 0) {
        int s = 0;
#pragma unroll
        for (int e = 0; e < NEXP; ++e) { meta[16 + e] = s; s += meta[e]; }
        meta[16 + NEXP] = s;   // == 4096 always
    }
}

__global__ void route_assign(const float* __restrict__ logits, int* __restrict__ meta,
                             int* __restrict__ rowTok, float* __restrict__ rowW) {
    int t = blockIdx.x * blockDim.x + threadIdx.x;
    int e0, e1; float w0, w1;
    top2_route(logits, t, e0, e1, w0, w1);
    int p0 = atomicAdd(&meta[8 + e0], 1);
    int s0 = meta[16 + e0] + p0;
    rowTok[s0] = t; rowW[s0] = w0;
    int p1 = atomicAdd(&meta[8 + e1], 1);
    int s1 = meta[16 + e1] + p1;
    rowTok[s1] = t; rowW[s1] = w1;
}

__global__ void gather_x(const float* __restrict__ x, const int* __restrict__ rowTok,
                         unsigned short* __restrict__ xg) {
    int slot = blockIdx.x;                // 4096 slots
    int tok = rowTok[slot];
    int c = threadIdx.x;                  // 256 threads * 8 cols = 2048
    const fl4* src = (const fl4*)(x + (size_t)tok * HID);
    fl4 a = src[c * 2], b = src[c * 2 + 1];
    short8 v;
    v[0] = (short)f2bf(a[0]); v[1] = (short)f2bf(a[1]); v[2] = (short)f2bf(a[2]); v[3] = (short)f2bf(a[3]);
    v[4] = (short)f2bf(b[0]); v[5] = (short)f2bf(b[1]); v[6] = (short)f2bf(b[2]); v[7] = (short)f2bf(b[3]);
    *(short8*)(xg + (size_t)slot * HID + c * 8) = v;
}

// GEMM1: for expert e, tokens chunk of 256 x (64 gate cols + 64 up cols), K=HID.
// B tile rows 0..63 = w1 rows (gate), rows 64..127 = w3 rows (up).
__global__ __launch_bounds__(512, 2) void gemm1_kernel(
        const unsigned short* __restrict__ xg,
        const float* __restrict__ w1, const float* __restrict__ w3,
        const int* __restrict__ meta, unsigned short* __restrict__ act) {
    int it = blockIdx.x;        // 88 tiles of 64 inter-cols
    int e  = blockIdx.y;        // 8
    int ch = blockIdx.z;        // 8 chunks of 256 rows
    int r0 = meta[16 + e];
    int Ne = meta[16 + e + 1] - r0;
    int cb = ch * 256;
    if (cb >= Ne) return;

    __shared__ __align__(16) short As[256][72];
    __shared__ __align__(16) short Bs[128][72];

    int tid = threadIdx.x;
    int lane = tid & 63, w = tid >> 6;

    f32x4 acc[2][8];
#pragma unroll
    for (int m = 0; m < 2; ++m)
#pragma unroll
        for (int n = 0; n < 8; ++n) acc[m][n] = (f32x4){0.f, 0.f, 0.f, 0.f};

    // staging coords
    int ar = tid >> 1, ah = (tid & 1) * 32;          // A: 256 rows x 64 cols bf16
    int asrow = cb + ar;
    const unsigned short* aptr = xg + (size_t)(r0 + (asrow < Ne ? asrow : 0)) * HID + ah;
    int br = tid >> 2, bq = (tid & 3) * 16;          // B: 128 rows x 64 cols fp32->bf16
    const float* wsrc = (br < 64)
        ? (w1 + ((size_t)e * NINT + (size_t)it * 64 + br) * HID + bq)
        : (w3 + ((size_t)e * NINT + (size_t)it * 64 + (br - 64)) * HID + bq);

    for (int k0 = 0; k0 < HID; k0 += 64) {
        int4v av[4];
#pragma unroll
        for (int i = 0; i < 4; ++i) av[i] = *(const int4v*)(aptr + k0 + i * 8);
        fl4 bv[4];
#pragma unroll
        for (int i = 0; i < 4; ++i) bv[i] = *(const fl4*)(wsrc + k0 + i * 4);
        short8 c0, c1;
#pragma unroll
        for (int i = 0; i < 4; ++i) { c0[i] = (short)f2bf(bv[0][i]); c0[i + 4] = (short)f2bf(bv[1][i]); }
#pragma unroll
        for (int i = 0; i < 4; ++i) { c1[i] = (short)f2bf(bv[2][i]); c1[i + 4] = (short)f2bf(bv[3][i]); }

#pragma unroll
        for (int i = 0; i < 4; ++i) *(int4v*)&As[ar][ah + i * 8] = av[i];
        *(short8*)&Bs[br][bq] = c0;
        *(short8*)&Bs[br][bq + 8] = c1;
        __syncthreads();

#pragma unroll
        for (int kk = 0; kk < 64; kk += 32) {
            int ko = kk + (lane >> 4) * 8;
            short8 a0 = *(const short8*)&As[w * 32 + (lane & 15)][ko];
            short8 a1 = *(const short8*)&As[w * 32 + 16 + (lane & 15)][ko];
#pragma unroll
            for (int n = 0; n < 8; ++n) {
                short8 b = *(const short8*)&Bs[n * 16 + (lane & 15)][ko];
                acc[0][n] = __builtin_amdgcn_mfma_f32_16x16x32_bf16(a0, b, acc[0][n], 0, 0, 0);
                acc[1][n] = __builtin_amdgcn_mfma_f32_16x16x32_bf16(a1, b, acc[1][n], 0, 0, 0);
            }
        }
        __syncthreads();
    }

    // epilogue: y = silu(gate) * up  -> act bf16
    int rq = lane >> 4, cl = lane & 15;
#pragma unroll
    for (int m = 0; m < 2; ++m) {
#pragma unroll
        for (int n = 0; n < 4; ++n) {
            f32x4 g = acc[m][n], u = acc[m][n + 4];
#pragma unroll
            for (int j = 0; j < 4; ++j) {
                int lr = w * 32 + m * 16 + rq * 4 + j;
                int srow = cb + lr;
                if (srow < Ne) {
                    float gv = g[j];
                    float y = gv / (1.f + __expf(-gv)) * u[j];
                    act[(size_t)(r0 + srow) * NINT + it * 64 + n * 16 + cl] = f2bf(y);
                }
            }
        }
    }
}

// GEMM2: y[rows, HID] = act[rows, NINT] @ w2[e]^T, scaled by routing weight, atomicAdd to out.
__global__ __launch_bounds__(512, 2) void gemm2_kernel(
        const unsigned short* __restrict__ act, const float* __restrict__ w2,
        const int* __restrict__ meta, const int* __restrict__ rowTok,
        const float* __restrict__ rowW, float* __restrict__ out) {
    int ht = blockIdx.x;        // 32 tiles of 64 hid-cols
    int e  = blockIdx.y;
    int ch = blockIdx.z;
    int r0 = meta[16 + e];
    int Ne = meta[16 + e + 1] - r0;
    int cb = ch * 256;
    if (cb >= Ne) return;

    __shared__ __align__(16) short As[256][72];
    __shared__ __align__(16) short Bs[64][72];

    int tid = threadIdx.x;
    int lane = tid & 63, w = tid >> 6;

    f32x4 acc[2][4];
#pragma unroll
    for (int m = 0; m < 2; ++m)
#pragma unroll
        for (int n = 0; n < 4; ++n) acc[m][n] = (f32x4){0.f, 0.f, 0.f, 0.f};

    int ar = tid >> 1, ah = (tid & 1) * 32;
    int asrow = cb + ar;
    const unsigned short* aptr = act + (size_t)(r0 + (asrow < Ne ? asrow : 0)) * NINT + ah;
    int br = tid >> 3, bq = (tid & 7) * 8;           // 64 rows x 64 cols fp32
    const float* bptr = w2 + ((size_t)e * HID + (size_t)ht * 64 + br) * NINT + bq;

    for (int k0 = 0; k0 < NINT; k0 += 64) {
        int4v av[4];
#pragma unroll
        for (int i = 0; i < 4; ++i) av[i] = *(const int4v*)(aptr + k0 + i * 8);
        fl4 bv0 = *(const fl4*)(bptr + k0);
        fl4 bv1 = *(const fl4*)(bptr + k0 + 4);
        short8 bc;
#pragma unroll
        for (int i = 0; i < 4; ++i) { bc[i] = (short)f2bf(bv0[i]); bc[i + 4] = (short)f2bf(bv1[i]); }

#pragma unroll
        for (int i = 0; i < 4; ++i) *(int4v*)&As[ar][ah + i * 8] = av[i];
        *(short8*)&Bs[br][bq] = bc;
        __syncthreads();

#pragma unroll
        for (int kk = 0; kk < 64; kk += 32) {
            int ko = kk + (lane >> 4) * 8;
            short8 a0 = *(const short8*)&As[w * 32 + (lane & 15)][ko];
            short8 a1 = *(const short8*)&As[w * 32 + 16 + (lane & 15)][ko];
#pragma unroll
            for (int n = 0; n < 4; ++n) {
                short8 b = *(const short8*)&Bs[n * 16 + (lane & 15)][ko];
                acc[0][n] = __builtin_amdgcn_mfma_f32_16x16x32_bf16(a0, b, acc[0][n], 0, 0, 0);
                acc[1][n] = __builtin_amdgcn_mfma_f32_16x16x32_bf16(a1, b, acc[1][n], 0, 0, 0);
            }
        }
        __syncthreads();
    }

    int rq = lane >> 4, cl = lane & 15;
#pragma unroll
    for (int m = 0; m < 2; ++m) {
#pragma unroll
        for (int j = 0; j < 4; ++j) {
            int lr = w * 32 + m * 16 + rq * 4 + j;
            int srow = cb + lr;
            if (srow < Ne) {
                int slot = r0 + srow;
                int tok = rowTok[slot];
                float sw = rowW[slot];
#pragma unroll
                for (int n = 0; n < 4; ++n) {
                    atomicAdd(&out[(size_t)tok * HID + ht * 64 + n * 16 + cl], acc[m][n][j] * sw);
                }
            }
        }
    }
}

extern "C" void kernel_launch(void* const* d_in, const int* in_sizes, int n_in,
                              void* d_out, int out_size, void* d_ws, size_t ws_size,
                              hipStream_t stream) {
    const float* x      = (const float*)d_in[0];
    const float* logits = (const float*)d_in[1];
    const float* w1     = (const float*)d_in[2];
    const float* w3     = (const float*)d_in[3];
    const float* w2     = (const float*)d_in[4];
    float* out = (float*)d_out;

    char* ws = (char*)d_ws;
    int*   meta   = (int*)ws;                       // 32 ints
    int*   rowTok = (int*)(ws + 512);               // 4096 ints
    float* rowW   = (float*)(ws + 512 + 16384);     // 4096 floats
    unsigned short* xg  = (unsigned short*)(ws + (1u << 20));   // 4096*2048 bf16 = 16 MB
    unsigned short* act = (unsigned short*)(ws + (18u << 20));  // 4096*5632 bf16 = 44 MB

    zero_kernel<<<4096, 256, 0, stream>>>(out, meta);
    route_count<<<8, 256, 0, stream>>>(logits, meta);
    scan_kernel<<<1, 1, 0, stream>>>(meta);
    route_assign<<<8, 256, 0, stream>>>(logits, meta, rowTok, rowW);
    gather_x<<<4096, 256, 0, stream>>>(x, rowTok, xg);
    gemm1_kernel<<<dim3(88, 8, 8), 512, 0, stream>>>(xg, w1, w3, meta, act);
    gemm2_kernel<<<dim3(32, 8, 8), 512, 0, stream>>>(act, w2, meta, rowTok, rowW, out);
}